// Round 9
// baseline (202.361 us; speedup 1.0000x reference)
//
#include <hip/hip_runtime.h>

// NCC loss, fused single pass. Layout [n][1][d][h][w], n=2, d=160, h=192, w=192, f32.
// R9: R6 structure (4-wave block, 64w x 16h, CD=6, 1944 blocks) with the per-step
//   __syncthreads (which forces s_waitcnt vmcnt(0) -- drains the DMA issued THIS
//   step) replaced by TRIPLE-buffered prefetch-distance-2 + raw s_barrier + manual
//   s_waitcnt vmcnt(3): at step t issue DMA for slice t+2, wait only for the DMA
//   issued at t-1 (slice t+1, ~1200 cyc in flight), leave the new one flying.
//   Per-wave vmcnt + barrier join => all waves' t+1 DMAs complete before any wave
//   starts step t+1. Tail/skipped-DMA steps use vmcnt(0) (wave-uniform cond).
//   R8 lesson: grid size >> traffic trims (CD=16's 720 blocks lost the co-resident
//   overlap; 101 us). R7 lesson: single-wave self-pacing fails. R4: DMA lanes
//   always active, CLAMPED addrs. R3: no occupancy clamp (ring spills).

namespace {
constexpr int Wd = 192, Hd = 192, Dd = 160;
constexpr int SH = 192;              // h stride (floats)
constexpr int SD = 192 * 192;        // d stride
constexpr long SN = (long)SD * Dd;   // n stride
constexpr int CD = 6;                // d outputs per chunk; T = CD+4 = 10
constexpr int NCHUNK = 27;           // ceil(160/6)
constexpr int TROW = 68;             // LDS row stride (floats): 17 segs of 16B
constexpr int ROWS = 20;             // h rows staged (16 outputs + 4 halo)
constexpr int SEGA = 17 * ROWS;      // 340 segs per array
constexpr int TILEF = 2 * ROWS * TROW; // 2720 floats per buffer (10.88 KB)
constexpr float INV_V = 1.0f / 125.0f;
constexpr float EPSf = 1e-5f;

// s_waitcnt imm (gfx9/CDNA): vmcnt[3:0]=imm[3:0], expcnt=imm[6:4],
// lgkmcnt=imm[11:8], vmcnt[5:4]=imm[15:14]. lgkm/exp set to max = no wait.
constexpr int WAITCNT_VM3 = 0x0F73;  // vmcnt(3), lgkm/exp untouched
constexpr int WAITCNT_VM0 = 0x0F70;  // vmcnt(0)

__device__ __forceinline__ void wslide(const float h[8], float o[4]) {
  float s0 = h[0] + h[1] + h[2] + h[3] + h[4];
  float s1 = s0 - h[0] + h[5];
  float s2 = s1 - h[1] + h[6];
  float s3 = s2 - h[2] + h[7];
  o[0] = s0; o[1] = s1; o[2] = s2; o[3] = s3;
}

__device__ __forceinline__ void gl_lds16(const float* g, float* l) {
  __builtin_amdgcn_global_load_lds(
      (const __attribute__((address_space(1))) void*)g,
      (__attribute__((address_space(3))) void*)l, 16, 0, 0);
}
} // namespace

__global__ __launch_bounds__(256) void ncc_fused(const float* __restrict__ I,
                                                 const float* __restrict__ Jv,
                                                 float* __restrict__ out) {
  __shared__ __align__(16) float tile[3][TILEF];   // 32.64 KB triple buffer
  __shared__ float red[4];

  const int tid = threadIdx.x;
  const int tx = tid & 15;        // w-run index (4 outputs each)
  const int ty = tid >> 4;        // h row within 16-tall tile
  const int wbase = blockIdx.x * 64;
  const int hbase = blockIdx.y * 16;
  const int n  = blockIdx.z / NCHUNK;
  const int d_lo = (blockIdx.z % NCHUNK) * CD;

  const float* Ib = I  + (long)n * SN;
  const float* Jb = Jv + (long)n * SN;

  // ---- staging descriptors: 680 16B-segs; wave w owns segs [w*170,(w+1)*170) ----
  const int wave = tid >> 6, lane = tid & 63;
  const float* gsrc = (wave >= 2) ? Jb : Ib;
  int goff[3]; int loff[3]; bool on[3];
  #pragma unroll
  for (int r = 0; r < 3; ++r) {
    const int seg = wave * 170 + r * 64 + lane;
    on[r] = (r < 2) || (lane < 42);               // lane 0 always active (DMA base!)
    const int rem = seg % SEGA;
    const int row = rem / 17, c16 = rem % 17;
    const int hh = hbase + row - 2;
    const int hc = min(max(hh, 0), Hd - 1);       // CLAMP, never mask (R4)
    const int gw = wbase - 2 + c16 * 4;
    const int gc = min(max(gw, 0), Wd - 4);
    goff[r] = hc * SH + gc;
    loff[r] = seg * 4;                            // float offset (seg*16 bytes)
  }

  // ---- prologue: stage slices for steps 0 and 1 into buffers 0 and 1 ----
  {
    const int s0 = d_lo - 2, s1 = d_lo - 1;
    if (s0 >= 0 && s0 < Dd) {
      const float* base = gsrc + (long)s0 * SD;
      #pragma unroll
      for (int r = 0; r < 3; ++r) if (on[r]) gl_lds16(base + goff[r], &tile[0][loff[r]]);
    }
    if (s1 >= 0 && s1 < Dd) {
      const float* base = gsrc + (long)s1 * SD;
      #pragma unroll
      for (int r = 0; r < 3; ++r) if (on[r]) gl_lds16(base + goff[r], &tile[1][loff[r]]);
    }
  }
  __builtin_amdgcn_s_waitcnt(WAITCNT_VM0);
  __builtin_amdgcn_s_barrier();

  // W-edge repair flags (clamped DMA fetch shifts 2 cols at the outer thread cols)
  const bool zl = (wbase == 0)   && (tx == 0);
  const bool zr = (wbase == 128) && (tx == 15);
  // H-interior tiles: all staged rows hbase-2..hbase+17 in bounds
  const bool hint = (hbase != 0) && (hbase != 176);

  float ring[5][5][4];   // [phase][channel:{I,J,II,JJ,IJ}][k]
  float Dsum[5][4];      // running D-window sums
  #pragma unroll
  for (int c = 0; c < 5; ++c)
    #pragma unroll
    for (int k = 0; k < 4; ++k) {
      Dsum[c][k] = 0.f;
      #pragma unroll
      for (int q = 0; q < 5; ++q) ring[q][c][k] = 0.f;
    }
  float acc = 0.0f;

  constexpr int T = CD + 4; // 10 steps; step t consumes slice s_t = d_lo-2+t
  #pragma unroll
  for (int t = 0; t < T; ++t) {
    const int p = t % 5;                      // ring phase (compile-time: full unroll)
    const int s = d_lo - 2 + t;               // slice in buffer t%3

    // ---- issue DMA for slice s_{t+2} = d_lo+t into buffer (t+2)%3 ----
    const bool issued = ((t + 2) < T) && ((d_lo + t) < Dd);  // d_lo+t >= 0 always
    if (issued) {
      const float* base = gsrc + (long)(d_lo + t) * SD;
      float* dst = &tile[(t + 2) % 3][0];
      #pragma unroll
      for (int r = 0; r < 3; ++r) if (on[r]) gl_lds16(base + goff[r], dst + loff[r]);
    }

    // ---- H-window accumulate from buffer t%3 ----
    float hsI[8], hsJ[8], hsII[8], hsJJ[8], hsIJ[8];
    const bool svalid = (s >= 0) && (s < Dd);
    if (svalid && hint) {
      // branch-free interior: first row initializes, rows 1..4 accumulate
      const float* bufc = &tile[t % 3][0];
      #pragma unroll
      for (int dh = 0; dh < 5; ++dh) {
        const float* pa = bufc + (ty + dh) * TROW + 4 * tx;  // 16B-aligned
        const float* pb = pa + ROWS * TROW;                  // J array
        float a[8], b[8];
        ((float4*)a)[0] = ((const float4*)pa)[0];
        ((float4*)a)[1] = ((const float4*)pa)[1];
        ((float4*)b)[0] = ((const float4*)pb)[0];
        ((float4*)b)[1] = ((const float4*)pb)[1];
        if (zl) { a[2]=a[0]; a[3]=a[1]; a[0]=0.f; a[1]=0.f;
                  b[2]=b[0]; b[3]=b[1]; b[0]=0.f; b[1]=0.f; }
        if (zr) { a[4]=a[6]; a[5]=a[7]; a[6]=0.f; a[7]=0.f;
                  b[4]=b[6]; b[5]=b[7]; b[6]=0.f; b[7]=0.f; }
        #pragma unroll
        for (int c = 0; c < 8; ++c) {
          const float x = a[c], y = b[c];
          if (dh == 0) {
            hsI[c] = x; hsJ[c] = y;
            hsII[c] = x * x; hsJJ[c] = y * y; hsIJ[c] = x * y;
          } else {
            hsI[c]  += x;
            hsJ[c]  += y;
            hsII[c] = fmaf(x, x, hsII[c]);
            hsJJ[c] = fmaf(y, y, hsJJ[c]);
            hsIJ[c] = fmaf(x, y, hsIJ[c]);
          }
        }
      }
    } else {
      #pragma unroll
      for (int c = 0; c < 8; ++c) {
        hsI[c] = 0.f; hsJ[c] = 0.f; hsII[c] = 0.f; hsJJ[c] = 0.f; hsIJ[c] = 0.f;
      }
      if (svalid) {                          // edge h tile: guarded rows
        const float* bufc = &tile[t % 3][0];
        #pragma unroll
        for (int dh = 0; dh < 5; ++dh) {
          const int hh = hbase + ty + dh - 2;
          if (hh >= 0 && hh < Hd) {          // skip clamped-duplicate halo rows
            const float* pa = bufc + (ty + dh) * TROW + 4 * tx;
            const float* pb = pa + ROWS * TROW;
            float a[8], b[8];
            ((float4*)a)[0] = ((const float4*)pa)[0];
            ((float4*)a)[1] = ((const float4*)pa)[1];
            ((float4*)b)[0] = ((const float4*)pb)[0];
            ((float4*)b)[1] = ((const float4*)pb)[1];
            if (zl) { a[2]=a[0]; a[3]=a[1]; a[0]=0.f; a[1]=0.f;
                      b[2]=b[0]; b[3]=b[1]; b[0]=0.f; b[1]=0.f; }
            if (zr) { a[4]=a[6]; a[5]=a[7]; a[6]=0.f; a[7]=0.f;
                      b[4]=b[6]; b[5]=b[7]; b[6]=0.f; b[7]=0.f; }
            #pragma unroll
            for (int c = 0; c < 8; ++c) {
              const float x = a[c], y = b[c];
              hsI[c]  += x;
              hsJ[c]  += y;
              hsII[c] = fmaf(x, x, hsII[c]);
              hsJJ[c] = fmaf(y, y, hsJJ[c]);
              hsIJ[c] = fmaf(x, y, hsIJ[c]);
            }
          }
        }
      }
    }

    // ---- W-window sliding sums -> ring slot p; running D-sum update ----
    float nw[5][4];
    wslide(hsI,  nw[0]);
    wslide(hsJ,  nw[1]);
    wslide(hsII, nw[2]);
    wslide(hsJJ, nw[3]);
    wslide(hsIJ, nw[4]);
    #pragma unroll
    for (int c = 0; c < 5; ++c)
      #pragma unroll
      for (int k = 0; k < 4; ++k) {
        Dsum[c][k] += nw[c][k] - ring[p][c][k];
        ring[p][c][k] = nw[c][k];
      }

    // ---- cc epilogue ----
    const int d = d_lo + t - 4;
    if (t >= 4 && d < Dd) {
      #pragma unroll
      for (int k = 0; k < 4; ++k) {
        const float SI = Dsum[0][k], SJ = Dsum[1][k];
        const float SII = Dsum[2][k], SJJ = Dsum[3][k], SIJ = Dsum[4][k];
        const float cross = SIJ - SI * SJ * INV_V;
        const float vI    = SII - SI * SI * INV_V;
        const float vJ    = SJJ - SJ * SJ * INV_V;
        acc += cross * cross / (vI * vJ + EPSf);
      }
    }

    // ---- fine-grained drain + raw barrier (NOT __syncthreads) ----
    // issued: leave this step's 3 DMAs flying, drain the older ones (vmcnt 3).
    // not issued (tail): drain everything so step t+1's buffer is ready.
    if (issued) __builtin_amdgcn_s_waitcnt(WAITCNT_VM3);
    else        __builtin_amdgcn_s_waitcnt(WAITCNT_VM0);
    __builtin_amdgcn_s_barrier();
  }

  // ---- block reduction -> single atomic per block ----
  #pragma unroll
  for (int off = 32; off > 0; off >>= 1) acc += __shfl_xor(acc, off, 64);
  if ((tid & 63) == 0) red[tid >> 6] = acc;
  __syncthreads();
  if (tid == 0) {
    const float total = red[0] + red[1] + red[2] + red[3];
    atomicAdd(out, total * (-1.0f / 11796480.0f)); // -mean over 2*160*192*192
  }
}

extern "C" void kernel_launch(void* const* d_in, const int* in_sizes, int n_in,
                              void* d_out, int out_size, void* d_ws, size_t ws_size,
                              hipStream_t stream) {
  const float* I = (const float*)d_in[0];
  const float* J = (const float*)d_in[1];
  float* out = (float*)d_out;
  hipMemsetAsync(out, 0, sizeof(float), stream);
  dim3 grid(3, 12, 2 * NCHUNK); // W tiles * H tiles * (n x 27 d-chunks of 6)
  ncc_fused<<<grid, 256, 0, stream>>>(I, J, out);
}

// Round 10
// 202.098 us; speedup vs baseline: 1.0013x; 1.0013x over previous
//
#include <hip/hip_runtime.h>

// NCC loss, fused single pass. Layout [n][1][d][h][w], n=2, d=160, h=192, w=192, f32.
// R10: R6 (champion, 85us) with ONE change: 128-thread / 2-wave blocks (32w x 16h).
//   Rationale: R6's pipes (VALU ~43us, LDS ~40us) alternate rather than overlap,
//   quantized by a barrier coupling 4 waves with only ~4 blocks/CU to interleave.
//   2-wave blocks halve the barrier domain and raise independent blocks/CU to ~6
//   (LDS 11.5 KB/block), so one block's vmcnt(0) drain is hidden by others.
//   Failed-experiment ledger: R7 single-wave barrier-free (compiler vmcnt(0) per
//   step, 108us); R8 CD=16 (720 blocks, lost overlap, 101us); R9 triple-buffer
//   +manual vmcnt (VGPR 232, 125us). R4: DMA lanes always active, CLAMPED addrs
//   (LDS dest = readfirstlane+lane*16). R3: no occupancy clamp (ring spills).
//   Kept: running Dsum (R6), interior first-row-init (R8), per-step __syncthreads.

namespace {
constexpr int Wd = 192, Hd = 192, Dd = 160;
constexpr int SH = 192;              // h stride (floats)
constexpr int SD = 192 * 192;        // d stride
constexpr long SN = (long)SD * Dd;   // n stride
constexpr int CD = 6;                // d outputs per chunk; T = CD+4 = 10
constexpr int NCHUNK = 27;           // ceil(160/6)
constexpr int TROW = 36;             // LDS row stride (floats): 9 segs of 16B
constexpr int ROWS = 20;             // h rows staged (16 outputs + 4 halo)
constexpr int SEGA = 9 * ROWS;       // 180 segs per array
constexpr int TILEF = 2 * ROWS * TROW; // 1440 floats per buffer (5.76 KB)
constexpr float INV_V = 1.0f / 125.0f;
constexpr float EPSf = 1e-5f;

__device__ __forceinline__ void wslide(const float h[8], float o[4]) {
  float s0 = h[0] + h[1] + h[2] + h[3] + h[4];
  float s1 = s0 - h[0] + h[5];
  float s2 = s1 - h[1] + h[6];
  float s3 = s2 - h[2] + h[7];
  o[0] = s0; o[1] = s1; o[2] = s2; o[3] = s3;
}

__device__ __forceinline__ void gl_lds16(const float* g, float* l) {
  __builtin_amdgcn_global_load_lds(
      (const __attribute__((address_space(1))) void*)g,
      (__attribute__((address_space(3))) void*)l, 16, 0, 0);
}
} // namespace

__global__ __launch_bounds__(128) void ncc_fused(const float* __restrict__ I,
                                                 const float* __restrict__ Jv,
                                                 float* __restrict__ out) {
  __shared__ float tile[2][TILEF];   // 11.52 KB double buffer
  __shared__ float red[2];

  const int tid = threadIdx.x;
  const int tx = tid & 7;         // w-run index (4 outputs each; 32 w total)
  const int ty = tid >> 3;        // h row within 16-tall tile
  const int wbase = blockIdx.x * 32;
  const int hbase = blockIdx.y * 16;
  const int n  = blockIdx.z / NCHUNK;
  const int d_lo = (blockIdx.z % NCHUNK) * CD;

  const float* Ib = I  + (long)n * SN;
  const float* Jb = Jv + (long)n * SN;

  // ---- staging descriptors: 360 16B-segs; wave 0 -> I, wave 1 -> J ----
  // Each wave: 180 segs = 2*64 + 52. seg layout: [row 0..19][c16 0..8], cols
  // wbase-2 .. wbase+33. LDS float-off = (arr*SEGA + seg)*4.
  const int wave = tid >> 6, lane = tid & 63;
  const float* gsrc = wave ? Jb : Ib;
  int goff[3]; int loff[3]; bool on[3];
  #pragma unroll
  for (int r = 0; r < 3; ++r) {
    const int seg = r * 64 + lane;                // 0..179 within this array
    on[r] = (r < 2) || (lane < 52);               // lane 0 always active (DMA base!)
    const int row = seg / 9, c16 = seg % 9;
    const int hh = hbase + row - 2;
    const int hc = min(max(hh, 0), Hd - 1);       // CLAMP, never mask (R4)
    const int gw = wbase - 2 + c16 * 4;
    const int gc = min(max(gw, 0), Wd - 4);
    goff[r] = hc * SH + gc;
    loff[r] = (wave * SEGA + seg) * 4;            // float offset (seg*16 bytes)
  }

  // ---- stage slice d_lo-2 into buffer 0 ----
  {
    const int s0 = d_lo - 2;
    if (s0 >= 0 && s0 < Dd) {
      const float* base = gsrc + (long)s0 * SD;
      #pragma unroll
      for (int r = 0; r < 3; ++r) if (on[r]) gl_lds16(base + goff[r], &tile[0][loff[r]]);
    }
  }
  __syncthreads();

  // W-edge repair flags (clamped DMA fetch shifts 2 cols at the outer thread cols)
  const bool zl = (wbase == 0)   && (tx == 0);
  const bool zr = (wbase == 160) && (tx == 7);
  // H-interior tiles: all staged rows hbase-2..hbase+17 in bounds
  const bool hint = (hbase != 0) && (hbase != 176);

  float ring[5][5][4];   // [phase][channel:{I,J,II,JJ,IJ}][k]
  float Dsum[5][4];      // running D-window sums
  #pragma unroll
  for (int c = 0; c < 5; ++c)
    #pragma unroll
    for (int k = 0; k < 4; ++k) {
      Dsum[c][k] = 0.f;
      #pragma unroll
      for (int q = 0; q < 5; ++q) ring[q][c][k] = 0.f;
    }
  float acc = 0.0f;

  constexpr int T = CD + 4; // 10 steps; output d = d_lo + t - 4 for t>=4
  for (int t0 = 0; t0 < T; t0 += 5) {
    #pragma unroll
    for (int p = 0; p < 5; ++p) {             // phase = t % 5
      const int t = t0 + p;
      const int s = d_lo - 2 + t;             // slice in current buffer

      // ---- DMA slice s+1 into the other buffer (overlaps this step's compute) ----
      {
        const int sn = s + 1;
        if ((t + 1) < T && sn >= 0 && sn < Dd) {   // wave-uniform condition
          const float* base = gsrc + (long)sn * SD;
          float* dst = &tile[(t + 1) & 1][0];
          #pragma unroll
          for (int r = 0; r < 3; ++r) if (on[r]) gl_lds16(base + goff[r], dst + loff[r]);
        }
      }

      // ---- H-window accumulate from current buffer ----
      float hsI[8], hsJ[8], hsII[8], hsJJ[8], hsIJ[8];
      const bool svalid = (s >= 0) && (s < Dd);
      if (svalid && hint) {
        // branch-free interior: first row initializes, rows 1..4 accumulate
        const float* bufc = &tile[t & 1][0];
        #pragma unroll
        for (int dh = 0; dh < 5; ++dh) {
          const float* pa = bufc + (ty + dh) * TROW + 4 * tx;  // 16B-aligned
          const float* pb = pa + ROWS * TROW;                  // J array
          float a[8], b[8];
          ((float4*)a)[0] = ((const float4*)pa)[0];
          ((float4*)a)[1] = ((const float4*)pa)[1];
          ((float4*)b)[0] = ((const float4*)pb)[0];
          ((float4*)b)[1] = ((const float4*)pb)[1];
          if (zl) { a[2]=a[0]; a[3]=a[1]; a[0]=0.f; a[1]=0.f;
                    b[2]=b[0]; b[3]=b[1]; b[0]=0.f; b[1]=0.f; }
          if (zr) { a[4]=a[6]; a[5]=a[7]; a[6]=0.f; a[7]=0.f;
                    b[4]=b[6]; b[5]=b[7]; b[6]=0.f; b[7]=0.f; }
          #pragma unroll
          for (int c = 0; c < 8; ++c) {
            const float x = a[c], y = b[c];
            if (dh == 0) {
              hsI[c] = x; hsJ[c] = y;
              hsII[c] = x * x; hsJJ[c] = y * y; hsIJ[c] = x * y;
            } else {
              hsI[c]  += x;
              hsJ[c]  += y;
              hsII[c] = fmaf(x, x, hsII[c]);
              hsJJ[c] = fmaf(y, y, hsJJ[c]);
              hsIJ[c] = fmaf(x, y, hsIJ[c]);
            }
          }
        }
      } else {
        #pragma unroll
        for (int c = 0; c < 8; ++c) {
          hsI[c] = 0.f; hsJ[c] = 0.f; hsII[c] = 0.f; hsJJ[c] = 0.f; hsIJ[c] = 0.f;
        }
        if (svalid) {                          // edge h tile: guarded rows
          const float* bufc = &tile[t & 1][0];
          #pragma unroll
          for (int dh = 0; dh < 5; ++dh) {
            const int hh = hbase + ty + dh - 2;
            if (hh >= 0 && hh < Hd) {          // skip clamped-duplicate halo rows
              const float* pa = bufc + (ty + dh) * TROW + 4 * tx;
              const float* pb = pa + ROWS * TROW;
              float a[8], b[8];
              ((float4*)a)[0] = ((const float4*)pa)[0];
              ((float4*)a)[1] = ((const float4*)pa)[1];
              ((float4*)b)[0] = ((const float4*)pb)[0];
              ((float4*)b)[1] = ((const float4*)pb)[1];
              if (zl) { a[2]=a[0]; a[3]=a[1]; a[0]=0.f; a[1]=0.f;
                        b[2]=b[0]; b[3]=b[1]; b[0]=0.f; b[1]=0.f; }
              if (zr) { a[4]=a[6]; a[5]=a[7]; a[6]=0.f; a[7]=0.f;
                        b[4]=b[6]; b[5]=b[7]; b[6]=0.f; b[7]=0.f; }
              #pragma unroll
              for (int c = 0; c < 8; ++c) {
                const float x = a[c], y = b[c];
                hsI[c]  += x;
                hsJ[c]  += y;
                hsII[c] = fmaf(x, x, hsII[c]);
                hsJJ[c] = fmaf(y, y, hsJJ[c]);
                hsIJ[c] = fmaf(x, y, hsIJ[c]);
              }
            }
          }
        }
      }

      // ---- W-window sliding sums -> ring slot p; running D-sum update ----
      float nw[5][4];
      wslide(hsI,  nw[0]);
      wslide(hsJ,  nw[1]);
      wslide(hsII, nw[2]);
      wslide(hsJJ, nw[3]);
      wslide(hsIJ, nw[4]);
      #pragma unroll
      for (int c = 0; c < 5; ++c)
        #pragma unroll
        for (int k = 0; k < 4; ++k) {
          Dsum[c][k] += nw[c][k] - ring[p][c][k];
          ring[p][c][k] = nw[c][k];
        }

      // ---- cc epilogue ----
      const int d = d_lo + t - 4;
      if (t >= 4 && d < Dd) {
        #pragma unroll
        for (int k = 0; k < 4; ++k) {
          const float SI = Dsum[0][k], SJ = Dsum[1][k];
          const float SII = Dsum[2][k], SJJ = Dsum[3][k], SIJ = Dsum[4][k];
          const float cross = SIJ - SI * SJ * INV_V;
          const float vI    = SII - SI * SI * INV_V;
          const float vJ    = SJJ - SJ * SJ * INV_V;
          acc += cross * cross / (vI * vJ + EPSf);
        }
      }

      __syncthreads();  // drains DMA for s+1; reads of current buffer done
    }
  }

  // ---- block reduction -> single atomic per block ----
  #pragma unroll
  for (int off = 32; off > 0; off >>= 1) acc += __shfl_xor(acc, off, 64);
  if ((tid & 63) == 0) red[tid >> 6] = acc;
  __syncthreads();
  if (tid == 0) {
    const float total = red[0] + red[1];
    atomicAdd(out, total * (-1.0f / 11796480.0f)); // -mean over 2*160*192*192
  }
}

extern "C" void kernel_launch(void* const* d_in, const int* in_sizes, int n_in,
                              void* d_out, int out_size, void* d_ws, size_t ws_size,
                              hipStream_t stream) {
  const float* I = (const float*)d_in[0];
  const float* J = (const float*)d_in[1];
  float* out = (float*)d_out;
  hipMemsetAsync(out, 0, sizeof(float), stream);
  dim3 grid(6, 12, 2 * NCHUNK); // 32-wide w tiles * 16-tall h tiles * (n x 27 chunks)
  ncc_fused<<<grid, 128, 0, stream>>>(I, J, out);
}